// Round 8
// baseline (1524.703 us; speedup 1.0000x reference)
//
#include <hip/hip_runtime.h>
#include <math.h>

#define NB   256
#define NN   1024
#define ND   64
#define NSL  8
#define NHID 128
#define N_SINK 8
#define N_MESH 4
#define F_LR  3.0f
#define F_EPS 1e-8f

// ---------------------------------------------------------------- k_pre
// x = LN(inputs)*g+b ; kk = |x@Wk^T|^2 ; wilog = x . wi_w + wi_b
__global__ __launch_bounds__(256) void k_pre(
    const float* __restrict__ inp, const float* __restrict__ Wk,
    const float* __restrict__ lng, const float* __restrict__ lnb,
    const float* __restrict__ wiw, const float* __restrict__ wib,
    float* __restrict__ xout, float* __restrict__ kkout, float* __restrict__ wilog) {
  __shared__ __align__(16) float xs[4][64];
  int wv = threadIdx.x >> 6, ln = threadIdx.x & 63;
  size_t row = (size_t)blockIdx.x * 4 + wv;        // < 262144
  float xi = inp[row * 64 + ln];
  float s1 = xi, s2 = xi * xi;
  #pragma unroll
  for (int m = 32; m >= 1; m >>= 1) { s1 += __shfl_xor(s1, m, 64); s2 += __shfl_xor(s2, m, 64); }
  float mean = s1 * (1.f / 64.f);
  float var  = s2 * (1.f / 64.f) - mean * mean;
  float xn = (xi - mean) * rsqrtf(var + 1e-5f) * lng[ln] + lnb[ln];
  xs[wv][ln] = xn;
  xout[row * 64 + ln] = xn;
  float wl = xn * wiw[ln];
  #pragma unroll
  for (int m = 32; m >= 1; m >>= 1) wl += __shfl_xor(wl, m, 64);
  __syncthreads();
  const float4* w4 = (const float4*)(Wk + ln * 64);
  const float4* x4 = (const float4*)xs[wv];
  float ko = 0.f;
  #pragma unroll
  for (int c = 0; c < 16; ++c) {
    float4 a = w4[c], xv = x4[c];
    ko += a.x * xv.x + a.y * xv.y + a.z * xv.z + a.w * xv.w;
  }
  float kk = ko * ko;
  #pragma unroll
  for (int m = 32; m >= 1; m >>= 1) kk += __shfl_xor(kk, m, 64);
  if (ln == 0) { kkout[row] = kk; wilog[row] = wl + wib[0]; }
}

// ---------------------------------------------------------------- helpers
__device__ __forceinline__ void wave_sum8(float* a) {
  #pragma unroll
  for (int m = 32; m >= 1; m >>= 1) {
    #pragma unroll
    for (int j = 0; j < 8; ++j) a[j] += __shfl_xor(a[j], m, 64);
  }
}

// ---------------------------------------------------------------- k_mega
// Multiplicative Sinkhorn, one barrier per half-step:
//  row step: per-thread fma over Mreg[8] (registers);
//  col step: per-wave butterfly partial -> part8 -> ONE barrier -> every wave
//  redundantly combines 16 partials (broadcast reads) -> g[8] in registers.
// know[8][1024] is written only once per iteration (final P / attn tile).
__global__ __launch_bounds__(1024) void k_mega(
    const float* __restrict__ noise, const float* __restrict__ mu,
    const float* __restrict__ sigma,
    const float* __restrict__ xg, const float* __restrict__ kkg,
    const float* __restrict__ wilogg,
    const float* __restrict__ Wq, const float* __restrict__ Wk,
    const float* __restrict__ Wv,
    const float* __restrict__ wih, const float* __restrict__ whh,
    const float* __restrict__ bih, const float* __restrict__ bhh,
    const float* __restrict__ fc1w, const float* __restrict__ fc1b,
    const float* __restrict__ fc2w, const float* __restrict__ fc2b,
    const float* __restrict__ lns_g, const float* __restrict__ lns_b,
    const float* __restrict__ lnf_g, const float* __restrict__ lnf_b,
    const float* __restrict__ wsw, const float* __restrict__ wsb,
    float* __restrict__ out_slots, float* __restrict__ out_pos,
    float* __restrict__ out_attn) {
  __shared__ __align__(16) float know[8][NN];    // 32 KB: attn tile (P)
  __shared__ __align__(16) union {
    float fhist[N_SINK][NN];    // phase B (f = exp(u) history)
    float part[16][8][64];      // phase C
  } U;
  __shared__ __align__(16) float part8[2][16][8]; // butterfly partials (dbuf)
  __shared__ __align__(16) float slot_lds[8][64];
  __shared__ __align__(16) float sn[8][64];      // slot LN; later updates row
  __shared__ __align__(16) float qsh[8][64];
  __shared__ __align__(16) float qs[8][64];
  __shared__ __align__(16) float updl[8][64];
  __shared__ __align__(16) float ys[8][64];
  __shared__ __align__(16) float rs[8][128];
  __shared__ float ghist[N_SINK][8];             // g history
  __shared__ float gBh[N_SINK][8];               // g/B history
  __shared__ float bmv[8], q2s[8], Bs[8], rBs[8];
  __shared__ float redf[16], bcf[1];

  int b = blockIdx.x, tid = threadIdx.x;
  int wv = tid >> 6, ln = tid & 63;

  // ---- slots init ----
  if (tid < 512) {
    slot_lds[tid >> 6][ln] = mu[ln] + (fabsf(sigma[ln]) + F_EPS) * noise[(size_t)b * 512 + tid];
  }
  // ---- A_i = 8*softmax(wilog)+eps ----
  float wl = wilogg[(size_t)b * NN + tid];
  float m0 = wl;
  #pragma unroll
  for (int s = 32; s >= 1; s >>= 1) m0 = fmaxf(m0, __shfl_xor(m0, s, 64));
  if (ln == 0) redf[wv] = m0;
  __syncthreads();
  if (tid == 0) { float a = redf[0]; for (int w = 1; w < 16; ++w) a = fmaxf(a, redf[w]); bcf[0] = a; }
  __syncthreads();
  m0 = bcf[0];
  float e0 = __expf(wl - m0), se0 = e0;
  #pragma unroll
  for (int s = 32; s >= 1; s >>= 1) se0 += __shfl_xor(se0, s, 64);
  __syncthreads();
  if (ln == 0) redf[wv] = se0;
  __syncthreads();
  if (tid == 0) { float a = 0.f; for (int w = 0; w < 16; ++w) a += redf[w]; bcf[0] = a; }
  __syncthreads();
  float Ai  = 8.f * e0 / bcf[0] + F_EPS;
  float rAi = __frcp_rn(Ai);
  float kk = kkg[(size_t)b * NN + tid];
  const float4* xrow4 = (const float4*)(xg + ((size_t)b * NN + tid) * ND);

  for (int it = 0; it < 3; ++it) {
    // ================= phase A: slotpre =================
    if (wv < 8) {
      float x = slot_lds[wv][ln];
      float s1 = x, s2 = x * x;
      #pragma unroll
      for (int m = 32; m >= 1; m >>= 1) { s1 += __shfl_xor(s1, m, 64); s2 += __shfl_xor(s2, m, 64); }
      float mean = s1 * (1.f / 64.f);
      float var  = s2 * (1.f / 64.f) - mean * mean;
      float xn = (x - mean) * rsqrtf(var + 1e-5f) * lns_g[ln] + lns_b[ln];
      sn[wv][ln] = xn;
      float wlg = xn * wsw[ln];
      #pragma unroll
      for (int m = 32; m >= 1; m >>= 1) wlg += __shfl_xor(wlg, m, 64);
      if (ln == 0) bmv[wv] = wlg + wsb[0];
    }
    __syncthreads();
    if (wv < 8) {
      const float4* w4 = (const float4*)(Wq + ln * 64);
      const float4* x4 = (const float4*)sn[wv];
      float q = 0.f;
      #pragma unroll
      for (int c = 0; c < 16; ++c) {
        float4 a = w4[c], xv = x4[c];
        q += a.x * xv.x + a.y * xv.y + a.z * xv.z + a.w * xv.w;
      }
      qsh[wv][ln] = q;
      float q2 = q * q;
      #pragma unroll
      for (int m = 32; m >= 1; m >>= 1) q2 += __shfl_xor(q2, m, 64);
      if (ln == 0) q2s[wv] = q2;
    }
    if (tid >= 512 && tid < 520) {   // B_j = 8*softmax(bmv)+eps
      int j = tid - 512;
      float mx = bmv[0];
      #pragma unroll
      for (int jj = 1; jj < 8; ++jj) mx = fmaxf(mx, bmv[jj]);
      float ss = 0.f;
      #pragma unroll
      for (int jj = 0; jj < 8; ++jj) ss += __expf(bmv[jj] - mx);
      float Bj = 8.f * __expf(bmv[j] - mx) / ss + F_EPS;
      Bs[j] = Bj; rBs[j] = __frcp_rn(Bj);
    }
    __syncthreads();
    if (wv < 8) {
      float qt = 0.f;
      for (int o = 0; o < 64; ++o) qt = fmaf(qsh[wv][o], Wk[o * 64 + ln], qt);
      qs[wv][ln] = qt;
    }
    __syncthreads();

    // ================= phase B: MESH + sinkhorn =================
    float Bsr = 0.f, rBsr = 0.f;
    if (ln < 8) { Bsr = Bs[ln]; rBsr = rBs[ln]; }
    float Mreg[8];
    {
      float dot[8];
      #pragma unroll
      for (int j = 0; j < 8; ++j) dot[j] = 0.f;
      #pragma unroll 4
      for (int c = 0; c < 16; ++c) {
        float4 xv = xrow4[c];
        #pragma unroll
        for (int j = 0; j < 8; ++j) {
          const float4 qv = *(const float4*)&qs[j][c * 4];
          dot[j] += xv.x * qv.x + xv.y * qv.y + xv.z * qv.z + xv.w * qv.w;
        }
      }
      #pragma unroll
      for (int j = 0; j < 8; ++j) {
        float d2 = kk + q2s[j] - 2.f * dot[j];
        Mreg[j] = __expf(-sqrtf(fmaxf(d2, 1e-12f)));
      }
    }
    float f = 0.f, g[8];
    for (int phase = 0; phase <= N_MESH; ++phase) {
      bool cold = (phase < N_MESH);
      // ---- forward: 8 sinkhorn iterations, 1 barrier each ----
      for (int t = 0; t < N_SINK; ++t) {
        float se = 0.f;
        if (cold && t == 0) {
          #pragma unroll
          for (int j = 0; j < 8; ++j) se += Mreg[j];
        } else {
          #pragma unroll
          for (int j = 0; j < 8; ++j) se += Mreg[j] * g[j];
        }
        f = __fdividef(Ai, se);
        U.fhist[t][tid] = f;
        float pp[8];
        #pragma unroll
        for (int j = 0; j < 8; ++j) pp[j] = Mreg[j] * f;
        wave_sum8(pp);
        if (ln == 0) {
          #pragma unroll
          for (int j = 0; j < 8; ++j) part8[t & 1][wv][j] = pp[j];
        }
        __syncthreads();
        float gv = 0.f;
        if (ln < 8) {
          float S = 0.f;
          #pragma unroll
          for (int w = 0; w < 16; ++w) S += part8[t & 1][w][ln];
          gv = __fdividef(Bsr, S);
          if (wv == 0) { ghist[t][ln] = gv; gBh[t][ln] = gv * rBsr; }
        }
        #pragma unroll
        for (int j = 0; j < 8; ++j) g[j] = __shfl(gv, j, 64);
      }
      if (phase == N_MESH) break;

      // ---- backward: dH/dK ----
      float Kbar[8], vbar[8], ubarT;
      {
        float pp[8], gsum = 0.f;
        #pragma unroll
        for (int j = 0; j < 8; ++j) {
          float P  = Mreg[j] * f * g[j];
          float pe = P + F_EPS;
          float gp = -(__logf(pe) + __fdividef(P, pe)) * P;
          Kbar[j] = gp; gsum += gp; pp[j] = gp;
        }
        ubarT = gsum;
        wave_sum8(pp);
        if (ln == 0) {
          #pragma unroll
          for (int j = 0; j < 8; ++j) part8[0][wv][j] = pp[j];
        }
        __syncthreads();
        float sv = 0.f;
        if (ln < 8) {
          float S = 0.f;
          #pragma unroll
          for (int w = 0; w < 16; ++w) S += part8[0][w][ln];
          sv = S;
        }
        #pragma unroll
        for (int j = 0; j < 8; ++j) vbar[j] = __shfl(sv, j, 64);
      }
      for (int t = N_SINK - 1; t >= 0; --t) {
        float ft = U.fhist[t][tid];
        float dsum = (t == N_SINK - 1) ? ubarT : 0.f;
        #pragma unroll
        for (int j = 0; j < 8; ++j) {
          float vw = vbar[j] * gBh[t][j] * (Mreg[j] * ft);
          Kbar[j] -= vw; dsum -= vw;
        }
        float dfa = dsum * ft * rAi;
        if (t > 0) {
          float pp[8];
          #pragma unroll
          for (int j = 0; j < 8; ++j) {
            float gm = ghist[t - 1][j];
            Kbar[j] -= dfa * Mreg[j] * gm;
            pp[j] = Mreg[j] * dfa;
          }
          wave_sum8(pp);
          if (ln == 0) {
            #pragma unroll
            for (int j = 0; j < 8; ++j) part8[t & 1][wv][j] = pp[j];
          }
          __syncthreads();
          float sv = 0.f;
          if (ln < 8) {
            float S = 0.f;
            #pragma unroll
            for (int w = 0; w < 16; ++w) S += part8[t & 1][w][ln];
            sv = -ghist[t - 1][ln] * S;
          }
          #pragma unroll
          for (int j = 0; j < 8; ++j) vbar[j] = __shfl(sv, j, 64);
        } else {
          #pragma unroll
          for (int j = 0; j < 8; ++j) Kbar[j] -= dfa * Mreg[j];   // g_prev = 1
        }
      }
      // M <- M * exp(-lr*Kbar)
      #pragma unroll
      for (int j = 0; j < 8; ++j) Mreg[j] *= __expf(-F_LR * Kbar[j]);
    }
    // ---- P = M*f*g -> know (attn tile), global on last iter ----
    #pragma unroll
    for (int j = 0; j < 8; ++j) {
      float P = Mreg[j] * f * g[j];
      know[j][tid] = P;
      if (it == 2) out_attn[((size_t)b * 8 + j) * NN + tid] = P;
    }
    __syncthreads();

    // ================= phase C: updates =================
    {
      float acc[8];
      #pragma unroll
      for (int j = 0; j < 8; ++j) acc[j] = 0.f;
      const float* xc = xg + ((size_t)b * NN + wv * 64) * ND + ln;
      #pragma unroll 2
      for (int i0 = 0; i0 < 64; i0 += 4) {
        float x0 = xc[(size_t)(i0 + 0) * 64];
        float x1 = xc[(size_t)(i0 + 1) * 64];
        float x2 = xc[(size_t)(i0 + 2) * 64];
        float x3 = xc[(size_t)(i0 + 3) * 64];
        int ir = wv * 64 + i0;
        #pragma unroll
        for (int j = 0; j < 8; ++j) {
          float4 a = *(const float4*)&know[j][ir];
          acc[j] += a.x * x0 + a.y * x1 + a.z * x2 + a.w * x3;
        }
      }
      #pragma unroll
      for (int j = 0; j < 8; ++j) U.part[wv][j][ln] = acc[j];
    }
    if (it == 2 && wv < 8) {   // slot_pos from final attn
      float px = 0.f, py = 0.f;
      #pragma unroll
      for (int k = 0; k < 16; ++k) {
        int i = ln + k * 64;
        float a = know[wv][i];
        px += a * (float)(i & 31);
        py += a * (float)(i >> 5);
      }
      #pragma unroll
      for (int m = 32; m >= 1; m >>= 1) { px += __shfl_xor(px, m, 64); py += __shfl_xor(py, m, 64); }
      if (ln == 0) {
        out_pos[(b * 8 + wv) * 2 + 0] = px * (1.f / 31.f);
        out_pos[(b * 8 + wv) * 2 + 1] = py * (1.f / 31.f);
      }
    }
    __syncthreads();
    if (wv < 8) {
      float s = 0.f;
      #pragma unroll
      for (int w = 0; w < 16; ++w) s += U.part[w][wv][ln];
      updl[wv][ln] = s;
    }
    __syncthreads();
    if (wv < 8) {
      const float4* w4 = (const float4*)(Wv + ln * 64);
      const float4* u4 = (const float4*)updl[wv];
      float updv = 0.f;
      #pragma unroll
      for (int c = 0; c < 16; ++c) {
        float4 uv = u4[c], wvv = w4[c];
        updv += uv.x * wvv.x + uv.y * wvv.y + uv.z * wvv.z + uv.w * wvv.w;
      }
      sn[wv][ln] = updv;   // reuse sn as the 'updates' row for GRU dots
    }
    __syncthreads();

    // ================= phase D: GRU + FF =================
    float hn = 0.f;
    if (wv < 8) {
      float h = slot_lds[wv][ln];
      float gi0 = bih[ln], gi1 = bih[64 + ln], gi2 = bih[128 + ln];
      float gh0 = bhh[ln], gh1 = bhh[64 + ln], gh2 = bhh[128 + ln];
      const float4* x4 = (const float4*)sn[wv];
      const float4* h4 = (const float4*)slot_lds[wv];
      const float4* wi0 = (const float4*)(wih + (size_t)ln * 64);
      const float4* wi1 = (const float4*)(wih + (size_t)(64 + ln) * 64);
      const float4* wi2 = (const float4*)(wih + (size_t)(128 + ln) * 64);
      const float4* wh0 = (const float4*)(whh + (size_t)ln * 64);
      const float4* wh1 = (const float4*)(whh + (size_t)(64 + ln) * 64);
      const float4* wh2 = (const float4*)(whh + (size_t)(128 + ln) * 64);
      #pragma unroll 2
      for (int c = 0; c < 16; ++c) {
        float4 xv = x4[c], hv = h4[c], a;
        a = wi0[c]; gi0 += xv.x * a.x + xv.y * a.y + xv.z * a.z + xv.w * a.w;
        a = wi1[c]; gi1 += xv.x * a.x + xv.y * a.y + xv.z * a.z + xv.w * a.w;
        a = wi2[c]; gi2 += xv.x * a.x + xv.y * a.y + xv.z * a.z + xv.w * a.w;
        a = wh0[c]; gh0 += hv.x * a.x + hv.y * a.y + hv.z * a.z + hv.w * a.w;
        a = wh1[c]; gh1 += hv.x * a.x + hv.y * a.y + hv.z * a.z + hv.w * a.w;
        a = wh2[c]; gh2 += hv.x * a.x + hv.y * a.y + hv.z * a.z + hv.w * a.w;
      }
      float r = 1.f / (1.f + expf(-(gi0 + gh0)));
      float z = 1.f / (1.f + expf(-(gi1 + gh1)));
      float n = tanhf(gi2 + r * gh2);
      hn = (1.f - z) * n + z * h;
      float s1 = hn, s2 = hn * hn;
      #pragma unroll
      for (int m = 32; m >= 1; m >>= 1) { s1 += __shfl_xor(s1, m, 64); s2 += __shfl_xor(s2, m, 64); }
      float mean = s1 * (1.f / 64.f);
      float var  = s2 * (1.f / 64.f) - mean * mean;
      ys[wv][ln] = (hn - mean) * rsqrtf(var + 1e-5f) * lnf_g[ln] + lnf_b[ln];
    }
    __syncthreads();
    if (wv < 8) {
      float a0 = fc1b[ln], a1 = fc1b[64 + ln];
      const float4* y4 = (const float4*)ys[wv];
      const float4* f0 = (const float4*)(fc1w + (size_t)ln * 64);
      const float4* f1 = (const float4*)(fc1w + (size_t)(64 + ln) * 64);
      #pragma unroll 2
      for (int c = 0; c < 16; ++c) {
        float4 yv = y4[c], a = f0[c], bb = f1[c];
        a0 += yv.x * a.x + yv.y * a.y + yv.z * a.z + yv.w * a.w;
        a1 += yv.x * bb.x + yv.y * bb.y + yv.z * bb.z + yv.w * bb.w;
      }
      rs[wv][ln] = fmaxf(a0, 0.f);
      rs[wv][64 + ln] = fmaxf(a1, 0.f);
    }
    __syncthreads();
    if (wv < 8) {
      float o = fc2b[ln];
      const float4* r4 = (const float4*)rs[wv];
      const float4* f2 = (const float4*)(fc2w + (size_t)ln * 128);
      #pragma unroll 2
      for (int c = 0; c < 32; ++c) {
        float4 rv = r4[c], a = f2[c];
        o += rv.x * a.x + rv.y * a.y + rv.z * a.z + rv.w * a.w;
      }
      slot_lds[wv][ln] = hn + o;
    }
    __syncthreads();
  }
  if (tid < 512) out_slots[(size_t)b * 512 + tid] = slot_lds[tid >> 6][ln];
}

// ---------------------------------------------------------------- launch
extern "C" void kernel_launch(void* const* d_in, const int* in_sizes, int n_in,
                              void* d_out, int out_size, void* d_ws, size_t ws_size,
                              hipStream_t stream) {
  const float* inputs = (const float*)d_in[0];
  const float* noise  = (const float*)d_in[1];
  const float* mu     = (const float*)d_in[2];
  const float* sigma  = (const float*)d_in[3];
  const float* Wq     = (const float*)d_in[4];
  const float* Wk     = (const float*)d_in[5];
  const float* Wv     = (const float*)d_in[6];
  const float* gwih   = (const float*)d_in[7];
  const float* gwhh   = (const float*)d_in[8];
  const float* gbih   = (const float*)d_in[9];
  const float* gbhh   = (const float*)d_in[10];
  const float* fc1w   = (const float*)d_in[11];
  const float* fc1b   = (const float*)d_in[12];
  const float* fc2w   = (const float*)d_in[13];
  const float* fc2b   = (const float*)d_in[14];
  const float* lnin_g = (const float*)d_in[15];
  const float* lnin_b = (const float*)d_in[16];
  const float* lns_g  = (const float*)d_in[17];
  const float* lns_b  = (const float*)d_in[18];
  const float* lnf_g  = (const float*)d_in[19];
  const float* lnf_b  = (const float*)d_in[20];
  const float* wi_w   = (const float*)d_in[21];
  const float* wi_b   = (const float*)d_in[22];
  const float* ws_w   = (const float*)d_in[23];
  const float* ws_b   = (const float*)d_in[24];

  float* out       = (float*)d_out;
  float* out_slots = out;                       // 256*8*64
  float* out_pos   = out + NB * NSL * ND;       // 256*8*2
  float* out_attn  = out_pos + NB * NSL * 2;    // 256*8*1024

  float* p = (float*)d_ws;
  float* xbuf  = p; p += (size_t)NB * NN * ND;  // 64 MB
  float* kkbuf = p; p += (size_t)NB * NN;
  float* wilog = p; p += (size_t)NB * NN;

  k_pre<<<(NB * NN) / 4, 256, 0, stream>>>(inputs, Wk, lnin_g, lnin_b, wi_w, wi_b,
                                           xbuf, kkbuf, wilog);
  k_mega<<<NB, 1024, 0, stream>>>(noise, mu, sigma, xbuf, kkbuf, wilog,
                                  Wq, Wk, Wv, gwih, gwhh, gbih, gbhh,
                                  fc1w, fc1b, fc2w, fc2b,
                                  lns_g, lns_b, lnf_g, lnf_b, ws_w, ws_b,
                                  out_slots, out_pos, out_attn);
}